// Round 11
// baseline (187.826 us; speedup 1.0000x reference)
//
#include <hip/hip_runtime.h>
#include <math.h>

#define N_PTS 8192
#define BATCH 2
#define KNB 16
#define NQ (BATCH * N_PTS)          // 16384

// spatial grid
#define H    0.35f
#define INVH (1.0f / 0.35f)
#define NC   30
#define LBOX (0.5f * H * NC)        // 5.25
#define NCELL (NC * NC * NC)        // 27000
#define MCELL (2 * NCELL)           // 54000 (both batches)
#define RMAXF 2                     // fast-path max ring
#define NCHK 8                      // slow-path chunks per query (1024 pts each)
#define CHKP (N_PTS / NCHK)         // 1024
#define SCANG 2048                  // slow-scan grid
#define MERGG 1024                  // slow-merge grid
#define WCAP 8192                   // pbuf capacity in queries (8 MB)

typedef unsigned long long u64;

__device__ __forceinline__ float med3f(float a, float b, float c) {
#if __has_builtin(__builtin_amdgcn_fmed3f)
    return __builtin_amdgcn_fmed3f(a, b, c);
#else
    return fmaxf(fminf(a, b), fminf(fmaxf(a, b), c));
#endif
}

__device__ __forceinline__ unsigned sortable(float x) {
    unsigned u = __float_as_uint(x);
    return u ^ ((unsigned)((int)u >> 31) | 0x80000000u);
}

// guarded u64 16-slot sorted insert (descending; pk[0]=max kept)
__device__ __forceinline__ void ins_u64(u64 (&pk)[KNB], u64 key) {
    if (key < pk[0]) {
#pragma unroll
        for (int s = 0; s < KNB; ++s) {
            const u64 ds1 = (s < KNB - 1) ? pk[s + 1] : 0ull;
            const bool c0 = key < pk[s];
            const bool c1 = key < ds1;
            pk[s] = c1 ? ds1 : (c0 ? key : pk[s]);
        }
    }
}

// 64-lane bitonic merge of per-lane sorted-desc u64[16] -> all lanes hold global top-16
__device__ __forceinline__ void merge64_u64(u64 (&pk)[KNB]) {
#pragma unroll
    for (int mm = 1; mm <= 32; mm <<= 1) {
        u64 L[KNB];
#pragma unroll
        for (int i = 0; i < KNB; ++i) {
            const u64 a = pk[i];
            const u64 c = __shfl_xor(pk[KNB - 1 - i], mm);
            L[i] = a < c ? a : c;
        }
#pragma unroll
        for (int dd = 8; dd >= 1; dd >>= 1) {
#pragma unroll
            for (int i = 0; i < KNB; ++i) {
                if ((i & dd) == 0) {
                    const u64 hi = L[i] > L[i | dd] ? L[i] : L[i | dd];
                    const u64 lo = L[i] > L[i | dd] ? L[i | dd] : L[i];
                    L[i] = hi; L[i | dd] = lo;
                }
            }
        }
#pragma unroll
        for (int i = 0; i < KNB; ++i) pk[i] = L[i];
    }
}

// ---------------- zero counters ----------------
__global__ __launch_bounds__(256) void kzero(int* __restrict__ p, int n) {
    const int i = blockIdx.x * 256 + threadIdx.x;
    if (i < n) p[i] = 0;
}

// ---------------- count points per cell ----------------
__global__ __launch_bounds__(256) void kcount(const float* __restrict__ pos,
                                              int* __restrict__ cnt,
                                              int* __restrict__ cellid) {
    const int g = blockIdx.x * 256 + threadIdx.x;
    const int b = g >> 13;
    const float x = pos[g * 3 + 0], y = pos[g * 3 + 1], z = pos[g * 3 + 2];
    int cx = (int)floorf((x + LBOX) * INVH); cx = min(max(cx, 0), NC - 1);
    int cy = (int)floorf((y + LBOX) * INVH); cy = min(max(cy, 0), NC - 1);
    int cz = (int)floorf((z + LBOX) * INVH); cz = min(max(cz, 0), NC - 1);
    const int c = (((b * NC) + cz) * NC + cy) * NC + cx;
    cellid[g] = c;
    atomicAdd(&cnt[c], 1);
}

// ---------------- prefix sum, level 1 ----------------
__global__ __launch_bounds__(1024) void kscan1(const int* __restrict__ cnt,
                                               int* __restrict__ scanned,
                                               int* __restrict__ bsum) {
    __shared__ int sh[1024];
    const int t = threadIdx.x;
    const int idx = blockIdx.x * 1024 + t;
    int v = (idx < MCELL) ? cnt[idx] : 0;
    sh[t] = v;
    __syncthreads();
    for (int off = 1; off < 1024; off <<= 1) {
        const int add = (t >= off) ? sh[t - off] : 0;
        __syncthreads();
        sh[t] += add;
        __syncthreads();
    }
    if (idx < MCELL) scanned[idx] = sh[t];
    if (t == 1023) bsum[blockIdx.x] = sh[1023];
}

// ---------------- prefix sum, level 2 ----------------
__global__ __launch_bounds__(1024) void kscan2(const int* __restrict__ scanned,
                                               const int* __restrict__ bsum,
                                               int* __restrict__ cell_start) {
    __shared__ int soff;
    const int t = threadIdx.x;
    const int blk = blockIdx.x;
    const int idx = blk * 1024 + t;
    if (t == 0) {
        int s = 0;
        for (int k = 0; k < blk; ++k) s += bsum[k];
        soff = s;
    }
    __syncthreads();
    if (idx < MCELL) cell_start[idx + 1] = scanned[idx] + soff;
    if (idx == 0) cell_start[0] = 0;
}

// ---------------- scatter points into cell-sorted order ----------------
__global__ __launch_bounds__(256) void kscatter(const float* __restrict__ pos,
                                                const int* __restrict__ cellid,
                                                const int* __restrict__ cell_start,
                                                int* __restrict__ cnt2,
                                                float4* __restrict__ spp,
                                                int* __restrict__ sidx) {
    const int g = blockIdx.x * 256 + threadIdx.x;
    const int c = cellid[g];
    const int off = atomicAdd(&cnt2[c], 1);
    const int p = cell_start[c] + off;
    const float x = pos[g * 3 + 0], y = pos[g * 3 + 1], z = pos[g * 3 + 2];
    spp[p] = make_float4(-2.f * x, -2.f * y, -2.f * z, fmaf(x, x, fmaf(y, y, z * z)));
    sidx[p] = g & (N_PTS - 1);
}

// ---------------- fast kNN: 16 lanes/query, rings R<=2, else overflow ----------------
__global__ __launch_bounds__(64) void ksearch_fast(const float4* __restrict__ spp,
                                                   const int* __restrict__ sidx,
                                                   const int* __restrict__ cs,
                                                   int* __restrict__ knn,
                                                   int* __restrict__ ovf_list,
                                                   int* __restrict__ ovf_cnt) {
    const int tid = threadIdx.x;
    const int li  = tid & 15;
    const int sq  = blockIdx.x * 4 + (tid >> 4);
    const int b   = sq >> 13;

    const float4 me = spp[sq];
    const float qx = -0.5f * me.x, qy = -0.5f * me.y, qz = -0.5f * me.z;
    const float qsq = me.w;
    int cx = (int)floorf((qx + LBOX) * INVH); cx = min(max(cx, 0), NC - 1);
    int cy = (int)floorf((qy + LBOX) * INVH); cy = min(max(cy, 0), NC - 1);
    int cz = (int)floorf((qz + LBOX) * INVH); cz = min(max(cz, 0), NC - 1);

    auto do_ring = [&](int R, auto&& body) {
        const int zlo = max(cz - R, 0), zhi = min(cz + R, NC - 1);
        const int ylo = max(cy - R, 0), yhi = min(cy + R, NC - 1);
        const int xlo = max(cx - R, 0), xhi = min(cx + R, NC - 1);
        for (int z = zlo; z <= zhi; ++z) {
            const bool zf = (z == cz - R) || (z == cz + R);
            for (int y = ylo; y <= yhi; ++y) {
                const bool face = zf || (y == cy - R) || (y == cy + R);
                const int rowb = (((b * NC) + z) * NC + y) * NC;
                if (face) {
                    const int st = cs[rowb + xlo], en = cs[rowb + xhi + 1];
                    for (int p = st + li; p < en; p += 16) body(p);
                } else {
                    const int xm = cx - R, xp = cx + R;
                    if (xm >= 0) {
                        const int st = cs[rowb + xm], en = cs[rowb + xm + 1];
                        for (int p = st + li; p < en; p += 16) body(p);
                    }
                    if (xp < NC) {
                        const int st = cs[rowb + xp], en = cs[rowb + xp + 1];
                        for (int p = st + li; p < en; p += 16) body(p);
                    }
                }
            }
        }
    };

    // ---- pass 1: per-lane top-16 float keys (guarded med3 chain) ----
    float d[KNB];
#pragma unroll
    for (int k = 0; k < KNB; ++k) d[k] = 3.4e38f;

    auto scan1 = [&](int p) {
        const float4 v = spp[p];
        const float x = fmaf(qx, v.x, fmaf(qy, v.y, fmaf(qz, v.z, v.w)));
        if (x < d[0]) {
#pragma unroll
            for (int s = 0; s < KNB - 1; ++s) d[s] = med3f(d[s], d[s + 1], x);
            d[KNB - 1] = fminf(d[KNB - 1], x);
        }
    };

    int Rfin = -1;
    for (int R = 0; R <= RMAXF; ++R) {
        do_ring(R, scan1);
        const float bxl = fmaf((float)(cx - R), H, -LBOX);
        const float bxh = fmaf((float)(cx + R + 1), H, -LBOX);
        const float byl = fmaf((float)(cy - R), H, -LBOX);
        const float byh = fmaf((float)(cy + R + 1), H, -LBOX);
        const float bzl = fmaf((float)(cz - R), H, -LBOX);
        const float bzh = fmaf((float)(cz + R + 1), H, -LBOX);
        const float m = fminf(fminf(fminf(qx - bxl, bxh - qx),
                                    fminf(qy - byl, byh - qy)),
                              fminf(qz - bzl, bzh - qz));
        if (m > 0.f) {
            const float Bf = fmaf(m, m, -1e-4f) - qsq;
            int c = 0;
#pragma unroll
            for (int k = 0; k < KNB; ++k) c += (d[k] <= Bf) ? 1 : 0;
#pragma unroll
            for (int off = 1; off < 16; off <<= 1) c += __shfl_xor(c, off);
            if (c >= KNB) { Rfin = R; break; }
        }
    }

    if (Rfin < 0) {
        if (li == 0) { const int s2 = atomicAdd(ovf_cnt, 1); ovf_list[s2] = sq; }
        return;
    }

    // ---- merge per-lane float tops -> global top-16 keys (all lanes) ----
#pragma unroll
    for (int mm = 1; mm <= 8; mm <<= 1) {
        float L[KNB];
#pragma unroll
        for (int i = 0; i < KNB; ++i)
            L[i] = fminf(d[i], __shfl_xor(d[KNB - 1 - i], mm));
#pragma unroll
        for (int dd = 8; dd >= 1; dd >>= 1) {
#pragma unroll
            for (int i = 0; i < KNB; ++i) {
                if ((i & dd) == 0) {
                    const float hi = fmaxf(L[i], L[i | dd]);
                    const float lo = fminf(L[i], L[i | dd]);
                    L[i] = hi; L[i | dd] = lo;
                }
            }
        }
#pragma unroll
        for (int i = 0; i < KNB; ++i) d[i] = L[i];
    }
    const float thr = d[0];           // exact global 16th-smallest key

    // ---- pass 2 (cache-hot): exact (key,idx) top-16 among x <= thr ----
    u64 pk[KNB];
#pragma unroll
    for (int k = 0; k < KNB; ++k) pk[k] = 0xFFFFFFFFFFFFFFFFull;

    auto scan2 = [&](int p) {
        const float4 v = spp[p];
        const float x = fmaf(qx, v.x, fmaf(qy, v.y, fmaf(qz, v.z, v.w)));
        if (x <= thr) {
            ins_u64(pk, ((u64)sortable(x) << 32) | (unsigned)sidx[p]);
        }
    };
    for (int R = 0; R <= Rfin; ++R) do_ring(R, scan2);

    // ---- u64 16-lane bitonic merge -> exact global top-16 (key,idx) ----
#pragma unroll
    for (int mm = 1; mm <= 8; mm <<= 1) {
        u64 L[KNB];
#pragma unroll
        for (int i = 0; i < KNB; ++i) {
            const u64 a = pk[i];
            const u64 c = __shfl_xor(pk[KNB - 1 - i], mm);
            L[i] = a < c ? a : c;
        }
#pragma unroll
        for (int dd = 8; dd >= 1; dd >>= 1) {
#pragma unroll
            for (int i = 0; i < KNB; ++i) {
                if ((i & dd) == 0) {
                    const u64 hi = L[i] > L[i | dd] ? L[i] : L[i | dd];
                    const u64 lo = L[i] > L[i | dd] ? L[i | dd] : L[i];
                    L[i] = hi; L[i | dd] = lo;
                }
            }
        }
#pragma unroll
        for (int i = 0; i < KNB; ++i) pk[i] = L[i];
    }

    const int qorig = sidx[sq];
    const int obase = ((b << 13) + qorig) * KNB;
    u64 sel = pk[0];
#pragma unroll
    for (int s = 1; s < KNB; ++s) sel = (li == s) ? pk[s] : sel;
    knn[obase + li] = (int)(unsigned)(sel & 0xFFFFFFFFull);
}

// ---------------- slow kNN scan: one wave per (overflow query, 1024-pt chunk) ----------------
// TLP fix: ~nov*8 waves (vs nov single waves) hide load latency regardless of
// its source; per-lane 16 candidates in 2x8 explicit batches (128-VGPR budget
// via launch_bounds(64,4) so the batches actually stay in flight).
__global__ __launch_bounds__(64, 4) void kslow_scan(const float4* __restrict__ spp,
                                                    const int* __restrict__ sidx,
                                                    const int* __restrict__ ovf_list,
                                                    const int* __restrict__ ovf_cnt,
                                                    u64* __restrict__ pbuf) {
    const int lane = threadIdx.x;
    const int ntask = min(*ovf_cnt, WCAP) * NCHK;

    for (int task = blockIdx.x; task < ntask; task += SCANG) {
        const int w = task >> 3;          // overflow slot
        const int c = task & (NCHK - 1);  // chunk
        const int sq = ovf_list[w];
        const int b  = sq >> 13;
        const float4 me = spp[sq];
        const float qx = -0.5f * me.x, qy = -0.5f * me.y, qz = -0.5f * me.z;
        const int cbase = (b << 13) + c * CHKP;

        u64 pk[KNB];
#pragma unroll
        for (int k = 0; k < KNB; ++k) pk[k] = 0xFFFFFFFFFFFFFFFFull;
        unsigned smax = 0xFFFFFFFFu;

        // 1024 pts / 64 lanes = 16 cands/lane = 2 batches of 8
#pragma unroll
        for (int t0 = 0; t0 < 2; ++t0) {
            const int tb = cbase + lane + t0 * 512;
            float4 v0 = spp[tb + 0 * 64];
            float4 v1 = spp[tb + 1 * 64];
            float4 v2 = spp[tb + 2 * 64];
            float4 v3 = spp[tb + 3 * 64];
            float4 v4 = spp[tb + 4 * 64];
            float4 v5 = spp[tb + 5 * 64];
            float4 v6 = spp[tb + 6 * 64];
            float4 v7 = spp[tb + 7 * 64];
            float xs[8];
            xs[0] = fmaf(qx, v0.x, fmaf(qy, v0.y, fmaf(qz, v0.z, v0.w)));
            xs[1] = fmaf(qx, v1.x, fmaf(qy, v1.y, fmaf(qz, v1.z, v1.w)));
            xs[2] = fmaf(qx, v2.x, fmaf(qy, v2.y, fmaf(qz, v2.z, v2.w)));
            xs[3] = fmaf(qx, v3.x, fmaf(qy, v3.y, fmaf(qz, v3.z, v3.w)));
            xs[4] = fmaf(qx, v4.x, fmaf(qy, v4.y, fmaf(qz, v4.z, v4.w)));
            xs[5] = fmaf(qx, v5.x, fmaf(qy, v5.y, fmaf(qz, v5.z, v5.w)));
            xs[6] = fmaf(qx, v6.x, fmaf(qy, v6.y, fmaf(qz, v6.z, v6.w)));
            xs[7] = fmaf(qx, v7.x, fmaf(qy, v7.y, fmaf(qz, v7.z, v7.w)));
#pragma unroll
            for (int u = 0; u < 8; ++u) {
                const unsigned sx = sortable(xs[u]);
                if (sx <= smax) {
                    ins_u64(pk, ((u64)sx << 32) | (unsigned)sidx[tb + u * 64]);
                    smax = (unsigned)(pk[0] >> 32);
                }
            }
        }

        merge64_u64(pk);   // exact chunk top-16, replicated across lanes

        u64 sel = pk[0];
#pragma unroll
        for (int s = 1; s < KNB; ++s) sel = (lane == s) ? pk[s] : sel;
        if (lane < KNB) pbuf[(size_t)task * KNB + lane] = sel;
    }
}

// ---------------- slow kNN merge: one wave per overflow query ----------------
__global__ __launch_bounds__(64) void kslow_merge(const float4* __restrict__ spp,
                                                  const int* __restrict__ sidx,
                                                  int* __restrict__ knn,
                                                  const int* __restrict__ ovf_list,
                                                  const int* __restrict__ ovf_cnt,
                                                  const u64* __restrict__ pbuf) {
    const int lane = threadIdx.x;
    const int nov = *ovf_cnt;

    for (int w = blockIdx.x; w < nov; w += MERGG) {
        const int sq = ovf_list[w];
        const int b  = sq >> 13;

        u64 pk[KNB];
#pragma unroll
        for (int k = 0; k < KNB; ++k) pk[k] = 0xFFFFFFFFFFFFFFFFull;

        if (w < WCAP) {
            // 8 chunks x 16 = 128 partials; 2 per lane
            const u64 a0 = pbuf[(size_t)w * (NCHK * KNB) + lane];
            const u64 a1 = pbuf[(size_t)w * (NCHK * KNB) + 64 + lane];
            ins_u64(pk, a0);
            ins_u64(pk, a1);
        } else {
            // fallback (never hit at realistic overflow counts): in-wave brute
            const float4 me = spp[sq];
            const float qx = -0.5f * me.x, qy = -0.5f * me.y, qz = -0.5f * me.z;
            const int base = b << 13;
            unsigned smax = 0xFFFFFFFFu;
            for (int t = lane; t < N_PTS; t += 64) {
                const float4 v = spp[base + t];
                const float x = fmaf(qx, v.x, fmaf(qy, v.y, fmaf(qz, v.z, v.w)));
                const unsigned sx = sortable(x);
                if (sx <= smax) {
                    ins_u64(pk, ((u64)sx << 32) | (unsigned)sidx[base + t]);
                    smax = (unsigned)(pk[0] >> 32);
                }
            }
        }

        merge64_u64(pk);

        const int qorig = sidx[sq];
        const int obase = ((b << 13) + qorig) * KNB;
        u64 sel = pk[0];
#pragma unroll
        for (int s = 1; s < KNB; ++s) sel = (lane == s) ? pk[s] : sel;
        if (lane < KNB) knn[obase + lane] = (int)(unsigned)(sel & 0xFFFFFFFFull);
    }
}

// ---------------- fused PT layer: per-edge MLPs + 16-lane shuffle softmax ----------------
__global__ __launch_bounds__(256) void pt_layer_f(const float* __restrict__ hin,
                                                  const float* __restrict__ pos,
                                                  const int* __restrict__ knn,
                                                  const float* __restrict__ wqkv,
                                                  const float* __restrict__ pw1,
                                                  const float* __restrict__ pb1,
                                                  const float* __restrict__ pw2,
                                                  const float* __restrict__ pb2,
                                                  const float* __restrict__ aw1,
                                                  const float* __restrict__ ab1,
                                                  const float* __restrict__ aw2,
                                                  const float* __restrict__ ab2,
                                                  float* __restrict__ hout,
                                                  const float* __restrict__ lw,
                                                  const float* __restrict__ lb,
                                                  float* __restrict__ out,
                                                  int last) {
    const int gt = blockIdx.x * 256 + threadIdx.x;
    const int qg = gt >> 4;
    const int j  = gt & 15;
    const int b  = qg >> 13;
    const int jj = knn[qg * KNB + j] & (N_PTS - 1);
    const int g  = (b << 13) + jj;

    const float hi0 = hin[qg * 3 + 0], hi1 = hin[qg * 3 + 1], hi2 = hin[qg * 3 + 2];
    const float hj0 = hin[g * 3 + 0],  hj1 = hin[g * 3 + 1],  hj2 = hin[g * 3 + 2];
    const float rx = pos[qg * 3 + 0] - pos[g * 3 + 0];
    const float ry = pos[qg * 3 + 1] - pos[g * 3 + 1];
    const float rz = pos[qg * 3 + 2] - pos[g * 3 + 2];

    const float q0 = fmaf(hi0, wqkv[0], fmaf(hi1, wqkv[9],  hi2 * wqkv[18]));
    const float q1 = fmaf(hi0, wqkv[1], fmaf(hi1, wqkv[10], hi2 * wqkv[19]));
    const float q2 = fmaf(hi0, wqkv[2], fmaf(hi1, wqkv[11], hi2 * wqkv[20]));
    const float k0 = fmaf(hj0, wqkv[3], fmaf(hj1, wqkv[12], hj2 * wqkv[21]));
    const float k1 = fmaf(hj0, wqkv[4], fmaf(hj1, wqkv[13], hj2 * wqkv[22]));
    const float k2 = fmaf(hj0, wqkv[5], fmaf(hj1, wqkv[14], hj2 * wqkv[23]));
    const float v0 = fmaf(hj0, wqkv[6], fmaf(hj1, wqkv[15], hj2 * wqkv[24]));
    const float v1 = fmaf(hj0, wqkv[7], fmaf(hj1, wqkv[16], hj2 * wqkv[25]));
    const float v2 = fmaf(hj0, wqkv[8], fmaf(hj1, wqkv[17], hj2 * wqkv[26]));

    float e0 = pb2[0], e1 = pb2[1], e2 = pb2[2];
#pragma unroll
    for (int hh = 0; hh < 32; ++hh) {
        float t = fmaf(rx, pw1[hh], fmaf(ry, pw1[32 + hh], fmaf(rz, pw1[64 + hh], pb1[hh])));
        t = fmaxf(t, 0.0f);
        e0 = fmaf(t, pw2[hh * 3 + 0], e0);
        e1 = fmaf(t, pw2[hh * 3 + 1], e1);
        e2 = fmaf(t, pw2[hh * 3 + 2], e2);
    }

    const float x0 = q0 - k0 + e0;
    const float x1 = q1 - k1 + e1;
    const float x2 = q2 - k2 + e2;

    float s0 = ab2[0], s1 = ab2[1], s2 = ab2[2];
#pragma unroll
    for (int hh = 0; hh < 12; ++hh) {
        float t = fmaf(x0, aw1[hh], fmaf(x1, aw1[12 + hh], fmaf(x2, aw1[24 + hh], ab1[hh])));
        t = fmaxf(t, 0.0f);
        s0 = fmaf(t, aw2[hh * 3 + 0], s0);
        s1 = fmaf(t, aw2[hh * 3 + 1], s1);
        s2 = fmaf(t, aw2[hh * 3 + 2], s2);
    }

    const float w0 = v0 + e0, w1 = v1 + e1, w2 = v2 + e2;

    float m0 = s0, m1 = s1, m2 = s2;
#pragma unroll
    for (int off = 1; off < 16; off <<= 1) {
        m0 = fmaxf(m0, __shfl_xor(m0, off));
        m1 = fmaxf(m1, __shfl_xor(m1, off));
        m2 = fmaxf(m2, __shfl_xor(m2, off));
    }
    const float ex0 = __expf(s0 - m0), ex1 = __expf(s1 - m1), ex2 = __expf(s2 - m2);
    float n0 = ex0 * w0, n1 = ex1 * w1, n2 = ex2 * w2;
    float den0 = ex0, den1 = ex1, den2 = ex2;
#pragma unroll
    for (int off = 1; off < 16; off <<= 1) {
        den0 += __shfl_xor(den0, off); n0 += __shfl_xor(n0, off);
        den1 += __shfl_xor(den1, off); n1 += __shfl_xor(n1, off);
        den2 += __shfl_xor(den2, off); n2 += __shfl_xor(n2, off);
    }

    if (j == 0) {
        const float h0 = 1.f / (1.f + __expf(-(n0 / den0)));
        const float h1 = 1.f / (1.f + __expf(-(n1 / den1)));
        const float h2 = 1.f / (1.f + __expf(-(n2 / den2)));
        if (!last) {
            hout[qg * 3 + 0] = h0;
            hout[qg * 3 + 1] = h1;
            hout[qg * 3 + 2] = h2;
        } else {
            const float o0 = fmaf(h0, lw[0], fmaf(h1, lw[2], fmaf(h2, lw[4], lb[0])));
            const float o1 = fmaf(h0, lw[1], fmaf(h1, lw[3], fmaf(h2, lw[5], lb[1])));
            const float mm = fmaxf(o0, o1);
            const float ea = __expf(o0 - mm), eb = __expf(o1 - mm);
            const float inv = 1.f / (ea + eb);
            out[qg * 2 + 0] = ea * inv;
            out[qg * 2 + 1] = eb * inv;
        }
    }
}

// ---------------- launch ----------------
extern "C" void kernel_launch(void* const* d_in, const int* in_sizes, int n_in,
                              void* d_out, int out_size, void* d_ws, size_t ws_size,
                              hipStream_t stream) {
    const float* feats = (const float*)d_in[0];
    const float* pos   = (const float*)d_in[1];
    const float* wqkv = (const float*)d_in[3];
    const float* pw1  = (const float*)d_in[4];
    const float* pb1  = (const float*)d_in[5];
    const float* pw2  = (const float*)d_in[6];
    const float* pb2  = (const float*)d_in[7];
    const float* aw1  = (const float*)d_in[8];
    const float* ab1  = (const float*)d_in[9];
    const float* aw2  = (const float*)d_in[10];
    const float* ab2  = (const float*)d_in[11];
    const float* lw   = (const float*)d_in[12];
    const float* lb   = (const float*)d_in[13];
    float* out = (float*)d_out;

    size_t o = 0;
    auto take = [&](size_t bytes) { size_t r = o; o += (bytes + 15) & ~(size_t)15; return r; };
    const size_t o_cnt   = take((size_t)(2 * MCELL + 4) * 4);  // cnt | cnt2 | ovf_cnt
    const size_t o_scan  = take((size_t)MCELL * 4);
    const size_t o_cs    = take((size_t)(MCELL + 1) * 4);
    const size_t o_bsum  = take((size_t)256 * 4);
    const size_t o_cid   = take((size_t)NQ * 4);
    const size_t o_spp   = take((size_t)NQ * 16);
    const size_t o_sidx  = take((size_t)NQ * 4);
    const size_t o_knn   = take((size_t)NQ * KNB * 4);
    const size_t o_ovfl  = take((size_t)NQ * 4);
    const size_t o_hA    = take((size_t)NQ * 3 * 4);
    const size_t o_hB    = take((size_t)NQ * 3 * 4);
    const size_t o_pbuf  = take((size_t)WCAP * NCHK * KNB * 8);  // 8 MB
    if (ws_size < o) return;

    char* ws = (char*)d_ws;
    int*    cnt     = (int*)(ws + o_cnt);
    int*    cnt2    = cnt + MCELL;
    int*    ovf_cnt = cnt + 2 * MCELL;
    int*    scan  = (int*)(ws + o_scan);
    int*    cs    = (int*)(ws + o_cs);
    int*    bsum  = (int*)(ws + o_bsum);
    int*    cid   = (int*)(ws + o_cid);
    float4* spp   = (float4*)(ws + o_spp);
    int*    sidx  = (int*)(ws + o_sidx);
    int*    knn   = (int*)(ws + o_knn);
    int*    ovfl  = (int*)(ws + o_ovfl);
    float*  hA    = (float*)(ws + o_hA);
    float*  hB    = (float*)(ws + o_hB);
    u64*    pbuf  = (u64*)(ws + o_pbuf);

    const int nscan = (MCELL + 1023) / 1024;

    kzero<<<(2 * MCELL + 1 + 255) / 256, 256, 0, stream>>>(cnt, 2 * MCELL + 1);
    kcount<<<NQ / 256, 256, 0, stream>>>(pos, cnt, cid);
    kscan1<<<nscan, 1024, 0, stream>>>(cnt, scan, bsum);
    kscan2<<<nscan, 1024, 0, stream>>>(scan, bsum, cs);
    kscatter<<<NQ / 256, 256, 0, stream>>>(pos, cid, cs, cnt2, spp, sidx);
    ksearch_fast<<<NQ / 4, 64, 0, stream>>>(spp, sidx, cs, knn, ovfl, ovf_cnt);
    kslow_scan<<<SCANG, 64, 0, stream>>>(spp, sidx, ovfl, ovf_cnt, pbuf);
    kslow_merge<<<MERGG, 64, 0, stream>>>(spp, sidx, knn, ovfl, ovf_cnt, pbuf);

    pt_layer_f<<<NQ * 16 / 256, 256, 0, stream>>>(feats, pos, knn,
        wqkv + 0, pw1 + 0, pb1 + 0, pw2 + 0, pb2 + 0,
        aw1 + 0, ab1 + 0, aw2 + 0, ab2 + 0,
        hA, lw, lb, out, 0);
    pt_layer_f<<<NQ * 16 / 256, 256, 0, stream>>>(hA, pos, knn,
        wqkv + 27, pw1 + 96, pb1 + 32, pw2 + 96, pb2 + 3,
        aw1 + 36, ab1 + 12, aw2 + 36, ab2 + 3,
        hB, lw, lb, out, 0);
    pt_layer_f<<<NQ * 16 / 256, 256, 0, stream>>>(hB, pos, knn,
        wqkv + 54, pw1 + 192, pb1 + 64, pw2 + 192, pb2 + 6,
        aw1 + 72, ab1 + 24, aw2 + 72, ab2 + 6,
        hB, lw, lb, out, 1);
}

// Round 12
// 137.642 us; speedup vs baseline: 1.3646x; 1.3646x over previous
//
#include <hip/hip_runtime.h>
#include <math.h>

#define N_PTS 8192
#define BATCH 2
#define KNB 16
#define NQ (BATCH * N_PTS)          // 16384

// spatial grid
#define H    0.35f
#define INVH (1.0f / 0.35f)
#define NC   30
#define LBOX (0.5f * H * NC)        // 5.25
#define NCELL (NC * NC * NC)        // 27000
#define MCELL (2 * NCELL)           // 54000 (both batches)
#define RMAXF 2                     // fast-path max ring
#define NCHK 8                      // slow-path chunks per query (1024 pts each)
#define CHKP (N_PTS / NCHK)         // 1024
#define SCANG 8192                  // slow-scan grid (one task per wave)
#define MERGG 1024                  // slow-merge grid
#define WCAP 8192                   // pbuf capacity in queries (8 MB)

typedef unsigned long long u64;

__device__ __forceinline__ float med3f(float a, float b, float c) {
#if __has_builtin(__builtin_amdgcn_fmed3f)
    return __builtin_amdgcn_fmed3f(a, b, c);
#else
    return fmaxf(fminf(a, b), fminf(fmaxf(a, b), c));
#endif
}

__device__ __forceinline__ unsigned sortable(float x) {
    unsigned u = __float_as_uint(x);
    return u ^ ((unsigned)((int)u >> 31) | 0x80000000u);
}

// guarded u64 16-slot sorted insert (descending; pk[0]=max kept)
__device__ __forceinline__ void ins_u64(u64 (&pk)[KNB], u64 key) {
    if (key < pk[0]) {
#pragma unroll
        for (int s = 0; s < KNB; ++s) {
            const u64 ds1 = (s < KNB - 1) ? pk[s + 1] : 0ull;
            const bool c0 = key < pk[s];
            const bool c1 = key < ds1;
            pk[s] = c1 ? ds1 : (c0 ? key : pk[s]);
        }
    }
}

// static 16-element bitonic sort network, DESCENDING (a[0]=max). All indices
// compile-time (rule #20); 80 compare-exchanges, fully ILP-parallel.
__device__ __forceinline__ void sort16_desc_u64(u64 (&a)[KNB]) {
#pragma unroll
    for (int k = 2; k <= 16; k <<= 1) {
#pragma unroll
        for (int j = k >> 1; j > 0; j >>= 1) {
#pragma unroll
            for (int i = 0; i < 16; ++i) {
                const int l = i ^ j;
                if (l > i) {
                    const bool dirDesc = ((i & k) == 0);
                    const u64 mx = a[i] > a[l] ? a[i] : a[l];
                    const u64 mn = a[i] > a[l] ? a[l] : a[i];
                    a[i] = dirDesc ? mx : mn;
                    a[l] = dirDesc ? mn : mx;
                }
            }
        }
    }
}

// 64-lane bitonic merge of per-lane sorted-desc u64[16] -> all lanes hold global top-16
__device__ __forceinline__ void merge64_u64(u64 (&pk)[KNB]) {
#pragma unroll
    for (int mm = 1; mm <= 32; mm <<= 1) {
        u64 L[KNB];
#pragma unroll
        for (int i = 0; i < KNB; ++i) {
            const u64 a = pk[i];
            const u64 c = __shfl_xor(pk[KNB - 1 - i], mm);
            L[i] = a < c ? a : c;
        }
#pragma unroll
        for (int dd = 8; dd >= 1; dd >>= 1) {
#pragma unroll
            for (int i = 0; i < KNB; ++i) {
                if ((i & dd) == 0) {
                    const u64 hi = L[i] > L[i | dd] ? L[i] : L[i | dd];
                    const u64 lo = L[i] > L[i | dd] ? L[i | dd] : L[i];
                    L[i] = hi; L[i | dd] = lo;
                }
            }
        }
#pragma unroll
        for (int i = 0; i < KNB; ++i) pk[i] = L[i];
    }
}

// ---------------- zero counters ----------------
__global__ __launch_bounds__(256) void kzero(int* __restrict__ p, int n) {
    const int i = blockIdx.x * 256 + threadIdx.x;
    if (i < n) p[i] = 0;
}

// ---------------- count points per cell ----------------
__global__ __launch_bounds__(256) void kcount(const float* __restrict__ pos,
                                              int* __restrict__ cnt,
                                              int* __restrict__ cellid) {
    const int g = blockIdx.x * 256 + threadIdx.x;
    const int b = g >> 13;
    const float x = pos[g * 3 + 0], y = pos[g * 3 + 1], z = pos[g * 3 + 2];
    int cx = (int)floorf((x + LBOX) * INVH); cx = min(max(cx, 0), NC - 1);
    int cy = (int)floorf((y + LBOX) * INVH); cy = min(max(cy, 0), NC - 1);
    int cz = (int)floorf((z + LBOX) * INVH); cz = min(max(cz, 0), NC - 1);
    const int c = (((b * NC) + cz) * NC + cy) * NC + cx;
    cellid[g] = c;
    atomicAdd(&cnt[c], 1);
}

// ---------------- prefix sum, level 1 ----------------
__global__ __launch_bounds__(1024) void kscan1(const int* __restrict__ cnt,
                                               int* __restrict__ scanned,
                                               int* __restrict__ bsum) {
    __shared__ int sh[1024];
    const int t = threadIdx.x;
    const int idx = blockIdx.x * 1024 + t;
    int v = (idx < MCELL) ? cnt[idx] : 0;
    sh[t] = v;
    __syncthreads();
    for (int off = 1; off < 1024; off <<= 1) {
        const int add = (t >= off) ? sh[t - off] : 0;
        __syncthreads();
        sh[t] += add;
        __syncthreads();
    }
    if (idx < MCELL) scanned[idx] = sh[t];
    if (t == 1023) bsum[blockIdx.x] = sh[1023];
}

// ---------------- prefix sum, level 2 ----------------
__global__ __launch_bounds__(1024) void kscan2(const int* __restrict__ scanned,
                                               const int* __restrict__ bsum,
                                               int* __restrict__ cell_start) {
    __shared__ int soff;
    const int t = threadIdx.x;
    const int blk = blockIdx.x;
    const int idx = blk * 1024 + t;
    if (t == 0) {
        int s = 0;
        for (int k = 0; k < blk; ++k) s += bsum[k];
        soff = s;
    }
    __syncthreads();
    if (idx < MCELL) cell_start[idx + 1] = scanned[idx] + soff;
    if (idx == 0) cell_start[0] = 0;
}

// ---------------- scatter points into cell-sorted order ----------------
__global__ __launch_bounds__(256) void kscatter(const float* __restrict__ pos,
                                                const int* __restrict__ cellid,
                                                const int* __restrict__ cell_start,
                                                int* __restrict__ cnt2,
                                                float4* __restrict__ spp,
                                                int* __restrict__ sidx) {
    const int g = blockIdx.x * 256 + threadIdx.x;
    const int c = cellid[g];
    const int off = atomicAdd(&cnt2[c], 1);
    const int p = cell_start[c] + off;
    const float x = pos[g * 3 + 0], y = pos[g * 3 + 1], z = pos[g * 3 + 2];
    spp[p] = make_float4(-2.f * x, -2.f * y, -2.f * z, fmaf(x, x, fmaf(y, y, z * z)));
    sidx[p] = g & (N_PTS - 1);
}

// ---------------- fast kNN: 16 lanes/query, rings R<=2, else overflow ----------------
__global__ __launch_bounds__(64) void ksearch_fast(const float4* __restrict__ spp,
                                                   const int* __restrict__ sidx,
                                                   const int* __restrict__ cs,
                                                   int* __restrict__ knn,
                                                   int* __restrict__ ovf_list,
                                                   int* __restrict__ ovf_cnt) {
    const int tid = threadIdx.x;
    const int li  = tid & 15;
    const int sq  = blockIdx.x * 4 + (tid >> 4);
    const int b   = sq >> 13;

    const float4 me = spp[sq];
    const float qx = -0.5f * me.x, qy = -0.5f * me.y, qz = -0.5f * me.z;
    const float qsq = me.w;
    int cx = (int)floorf((qx + LBOX) * INVH); cx = min(max(cx, 0), NC - 1);
    int cy = (int)floorf((qy + LBOX) * INVH); cy = min(max(cy, 0), NC - 1);
    int cz = (int)floorf((qz + LBOX) * INVH); cz = min(max(cz, 0), NC - 1);

    auto do_ring = [&](int R, auto&& body) {
        const int zlo = max(cz - R, 0), zhi = min(cz + R, NC - 1);
        const int ylo = max(cy - R, 0), yhi = min(cy + R, NC - 1);
        const int xlo = max(cx - R, 0), xhi = min(cx + R, NC - 1);
        for (int z = zlo; z <= zhi; ++z) {
            const bool zf = (z == cz - R) || (z == cz + R);
            for (int y = ylo; y <= yhi; ++y) {
                const bool face = zf || (y == cy - R) || (y == cy + R);
                const int rowb = (((b * NC) + z) * NC + y) * NC;
                if (face) {
                    const int st = cs[rowb + xlo], en = cs[rowb + xhi + 1];
                    for (int p = st + li; p < en; p += 16) body(p);
                } else {
                    const int xm = cx - R, xp = cx + R;
                    if (xm >= 0) {
                        const int st = cs[rowb + xm], en = cs[rowb + xm + 1];
                        for (int p = st + li; p < en; p += 16) body(p);
                    }
                    if (xp < NC) {
                        const int st = cs[rowb + xp], en = cs[rowb + xp + 1];
                        for (int p = st + li; p < en; p += 16) body(p);
                    }
                }
            }
        }
    };

    // ---- pass 1: per-lane top-16 float keys (guarded med3 chain) ----
    float d[KNB];
#pragma unroll
    for (int k = 0; k < KNB; ++k) d[k] = 3.4e38f;

    auto scan1 = [&](int p) {
        const float4 v = spp[p];
        const float x = fmaf(qx, v.x, fmaf(qy, v.y, fmaf(qz, v.z, v.w)));
        if (x < d[0]) {
#pragma unroll
            for (int s = 0; s < KNB - 1; ++s) d[s] = med3f(d[s], d[s + 1], x);
            d[KNB - 1] = fminf(d[KNB - 1], x);
        }
    };

    int Rfin = -1;
    for (int R = 0; R <= RMAXF; ++R) {
        do_ring(R, scan1);
        const float bxl = fmaf((float)(cx - R), H, -LBOX);
        const float bxh = fmaf((float)(cx + R + 1), H, -LBOX);
        const float byl = fmaf((float)(cy - R), H, -LBOX);
        const float byh = fmaf((float)(cy + R + 1), H, -LBOX);
        const float bzl = fmaf((float)(cz - R), H, -LBOX);
        const float bzh = fmaf((float)(cz + R + 1), H, -LBOX);
        const float m = fminf(fminf(fminf(qx - bxl, bxh - qx),
                                    fminf(qy - byl, byh - qy)),
                              fminf(qz - bzl, bzh - qz));
        if (m > 0.f) {
            const float Bf = fmaf(m, m, -1e-4f) - qsq;
            int c = 0;
#pragma unroll
            for (int k = 0; k < KNB; ++k) c += (d[k] <= Bf) ? 1 : 0;
#pragma unroll
            for (int off = 1; off < 16; off <<= 1) c += __shfl_xor(c, off);
            if (c >= KNB) { Rfin = R; break; }
        }
    }

    if (Rfin < 0) {
        if (li == 0) { const int s2 = atomicAdd(ovf_cnt, 1); ovf_list[s2] = sq; }
        return;
    }

    // ---- merge per-lane float tops -> global top-16 keys (all lanes) ----
#pragma unroll
    for (int mm = 1; mm <= 8; mm <<= 1) {
        float L[KNB];
#pragma unroll
        for (int i = 0; i < KNB; ++i)
            L[i] = fminf(d[i], __shfl_xor(d[KNB - 1 - i], mm));
#pragma unroll
        for (int dd = 8; dd >= 1; dd >>= 1) {
#pragma unroll
            for (int i = 0; i < KNB; ++i) {
                if ((i & dd) == 0) {
                    const float hi = fmaxf(L[i], L[i | dd]);
                    const float lo = fminf(L[i], L[i | dd]);
                    L[i] = hi; L[i | dd] = lo;
                }
            }
        }
#pragma unroll
        for (int i = 0; i < KNB; ++i) d[i] = L[i];
    }
    const float thr = d[0];           // exact global 16th-smallest key

    // ---- pass 2 (cache-hot): exact (key,idx) top-16 among x <= thr ----
    u64 pk[KNB];
#pragma unroll
    for (int k = 0; k < KNB; ++k) pk[k] = 0xFFFFFFFFFFFFFFFFull;

    auto scan2 = [&](int p) {
        const float4 v = spp[p];
        const float x = fmaf(qx, v.x, fmaf(qy, v.y, fmaf(qz, v.z, v.w)));
        if (x <= thr) {
            ins_u64(pk, ((u64)sortable(x) << 32) | (unsigned)sidx[p]);
        }
    };
    for (int R = 0; R <= Rfin; ++R) do_ring(R, scan2);

    // ---- u64 16-lane bitonic merge -> exact global top-16 (key,idx) ----
#pragma unroll
    for (int mm = 1; mm <= 8; mm <<= 1) {
        u64 L[KNB];
#pragma unroll
        for (int i = 0; i < KNB; ++i) {
            const u64 a = pk[i];
            const u64 c = __shfl_xor(pk[KNB - 1 - i], mm);
            L[i] = a < c ? a : c;
        }
#pragma unroll
        for (int dd = 8; dd >= 1; dd >>= 1) {
#pragma unroll
            for (int i = 0; i < KNB; ++i) {
                if ((i & dd) == 0) {
                    const u64 hi = L[i] > L[i | dd] ? L[i] : L[i | dd];
                    const u64 lo = L[i] > L[i | dd] ? L[i | dd] : L[i];
                    L[i] = hi; L[i | dd] = lo;
                }
            }
        }
#pragma unroll
        for (int i = 0; i < KNB; ++i) pk[i] = L[i];
    }

    const int qorig = sidx[sq];
    const int obase = ((b << 13) + qorig) * KNB;
    u64 sel = pk[0];
#pragma unroll
    for (int s = 1; s < KNB; ++s) sel = (li == s) ? pk[s] : sel;
    knn[obase + li] = (int)(unsigned)(sel & 0xFFFFFFFFull);
}

// ---------------- slow kNN scan: one wave per (overflow query, 1024-pt chunk) ----------------
// Each lane owns exactly 16 candidates: load spp AND sidx unconditionally in
// 8-wide batches (no guard, no serial chain), build u64 keys directly into
// pk[0..15], then a static 16-elem bitonic sort (80 parallel CEs, replaces
// 16 serial 130-op guarded inserts), then the 64-lane merge. Grid = one task
// per wave for TLP.
__global__ __launch_bounds__(64, 4) void kslow_scan(const float4* __restrict__ spp,
                                                    const int* __restrict__ sidx,
                                                    const int* __restrict__ ovf_list,
                                                    const int* __restrict__ ovf_cnt,
                                                    u64* __restrict__ pbuf) {
    const int lane = threadIdx.x;
    const int ntask = min(*ovf_cnt, WCAP) * NCHK;

    for (int task = blockIdx.x; task < ntask; task += SCANG) {
        const int w = task >> 3;          // overflow slot
        const int c = task & (NCHK - 1);  // chunk
        const int sq = ovf_list[w];
        const int b  = sq >> 13;
        const float4 me = spp[sq];
        const float qx = -0.5f * me.x, qy = -0.5f * me.y, qz = -0.5f * me.z;
        const int cbase = (b << 13) + c * CHKP;

        u64 pk[KNB];
#pragma unroll
        for (int t0 = 0; t0 < 2; ++t0) {
            const int tb = cbase + lane + t0 * 512;
            float4 v[8];
            int id[8];
#pragma unroll
            for (int u = 0; u < 8; ++u) v[u] = spp[tb + u * 64];
#pragma unroll
            for (int u = 0; u < 8; ++u) id[u] = sidx[tb + u * 64];
#pragma unroll
            for (int u = 0; u < 8; ++u) {
                const float x = fmaf(qx, v[u].x, fmaf(qy, v[u].y, fmaf(qz, v[u].z, v[u].w)));
                pk[t0 * 8 + u] = ((u64)sortable(x) << 32) | (unsigned)id[u];
            }
        }

        sort16_desc_u64(pk);   // lane's 16 candidates, sorted desc
        merge64_u64(pk);       // exact chunk top-16, replicated across lanes

        u64 sel = pk[0];
#pragma unroll
        for (int s = 1; s < KNB; ++s) sel = (lane == s) ? pk[s] : sel;
        if (lane < KNB) pbuf[(size_t)task * KNB + lane] = sel;
    }
}

// ---------------- slow kNN merge: one wave per overflow query ----------------
__global__ __launch_bounds__(64) void kslow_merge(const float4* __restrict__ spp,
                                                  const int* __restrict__ sidx,
                                                  int* __restrict__ knn,
                                                  const int* __restrict__ ovf_list,
                                                  const int* __restrict__ ovf_cnt,
                                                  const u64* __restrict__ pbuf) {
    const int lane = threadIdx.x;
    const int nov = *ovf_cnt;

    for (int w = blockIdx.x; w < nov; w += MERGG) {
        const int sq = ovf_list[w];
        const int b  = sq >> 13;

        u64 pk[KNB];
#pragma unroll
        for (int k = 0; k < KNB; ++k) pk[k] = 0xFFFFFFFFFFFFFFFFull;

        if (w < WCAP) {
            // 8 chunks x 16 = 128 partials; 2 per lane
            const u64 a0 = pbuf[(size_t)w * (NCHK * KNB) + lane];
            const u64 a1 = pbuf[(size_t)w * (NCHK * KNB) + 64 + lane];
            ins_u64(pk, a0);
            ins_u64(pk, a1);
        } else {
            // fallback (never hit at realistic overflow counts): in-wave brute
            const float4 me = spp[sq];
            const float qx = -0.5f * me.x, qy = -0.5f * me.y, qz = -0.5f * me.z;
            const int base = b << 13;
            unsigned smax = 0xFFFFFFFFu;
            for (int t = lane; t < N_PTS; t += 64) {
                const float4 v = spp[base + t];
                const float x = fmaf(qx, v.x, fmaf(qy, v.y, fmaf(qz, v.z, v.w)));
                const unsigned sx = sortable(x);
                if (sx <= smax) {
                    ins_u64(pk, ((u64)sx << 32) | (unsigned)sidx[base + t]);
                    smax = (unsigned)(pk[0] >> 32);
                }
            }
        }

        merge64_u64(pk);

        const int qorig = sidx[sq];
        const int obase = ((b << 13) + qorig) * KNB;
        u64 sel = pk[0];
#pragma unroll
        for (int s = 1; s < KNB; ++s) sel = (lane == s) ? pk[s] : sel;
        if (lane < KNB) knn[obase + lane] = (int)(unsigned)(sel & 0xFFFFFFFFull);
    }
}

// ---------------- fused PT layer: per-edge MLPs + 16-lane shuffle softmax ----------------
__global__ __launch_bounds__(256) void pt_layer_f(const float* __restrict__ hin,
                                                  const float* __restrict__ pos,
                                                  const int* __restrict__ knn,
                                                  const float* __restrict__ wqkv,
                                                  const float* __restrict__ pw1,
                                                  const float* __restrict__ pb1,
                                                  const float* __restrict__ pw2,
                                                  const float* __restrict__ pb2,
                                                  const float* __restrict__ aw1,
                                                  const float* __restrict__ ab1,
                                                  const float* __restrict__ aw2,
                                                  const float* __restrict__ ab2,
                                                  float* __restrict__ hout,
                                                  const float* __restrict__ lw,
                                                  const float* __restrict__ lb,
                                                  float* __restrict__ out,
                                                  int last) {
    const int gt = blockIdx.x * 256 + threadIdx.x;
    const int qg = gt >> 4;
    const int j  = gt & 15;
    const int b  = qg >> 13;
    const int jj = knn[qg * KNB + j] & (N_PTS - 1);
    const int g  = (b << 13) + jj;

    const float hi0 = hin[qg * 3 + 0], hi1 = hin[qg * 3 + 1], hi2 = hin[qg * 3 + 2];
    const float hj0 = hin[g * 3 + 0],  hj1 = hin[g * 3 + 1],  hj2 = hin[g * 3 + 2];
    const float rx = pos[qg * 3 + 0] - pos[g * 3 + 0];
    const float ry = pos[qg * 3 + 1] - pos[g * 3 + 1];
    const float rz = pos[qg * 3 + 2] - pos[g * 3 + 2];

    const float q0 = fmaf(hi0, wqkv[0], fmaf(hi1, wqkv[9],  hi2 * wqkv[18]));
    const float q1 = fmaf(hi0, wqkv[1], fmaf(hi1, wqkv[10], hi2 * wqkv[19]));
    const float q2 = fmaf(hi0, wqkv[2], fmaf(hi1, wqkv[11], hi2 * wqkv[20]));
    const float k0 = fmaf(hj0, wqkv[3], fmaf(hj1, wqkv[12], hj2 * wqkv[21]));
    const float k1 = fmaf(hj0, wqkv[4], fmaf(hj1, wqkv[13], hj2 * wqkv[22]));
    const float k2 = fmaf(hj0, wqkv[5], fmaf(hj1, wqkv[14], hj2 * wqkv[23]));
    const float v0 = fmaf(hj0, wqkv[6], fmaf(hj1, wqkv[15], hj2 * wqkv[24]));
    const float v1 = fmaf(hj0, wqkv[7], fmaf(hj1, wqkv[16], hj2 * wqkv[25]));
    const float v2 = fmaf(hj0, wqkv[8], fmaf(hj1, wqkv[17], hj2 * wqkv[26]));

    float e0 = pb2[0], e1 = pb2[1], e2 = pb2[2];
#pragma unroll
    for (int hh = 0; hh < 32; ++hh) {
        float t = fmaf(rx, pw1[hh], fmaf(ry, pw1[32 + hh], fmaf(rz, pw1[64 + hh], pb1[hh])));
        t = fmaxf(t, 0.0f);
        e0 = fmaf(t, pw2[hh * 3 + 0], e0);
        e1 = fmaf(t, pw2[hh * 3 + 1], e1);
        e2 = fmaf(t, pw2[hh * 3 + 2], e2);
    }

    const float x0 = q0 - k0 + e0;
    const float x1 = q1 - k1 + e1;
    const float x2 = q2 - k2 + e2;

    float s0 = ab2[0], s1 = ab2[1], s2 = ab2[2];
#pragma unroll
    for (int hh = 0; hh < 12; ++hh) {
        float t = fmaf(x0, aw1[hh], fmaf(x1, aw1[12 + hh], fmaf(x2, aw1[24 + hh], ab1[hh])));
        t = fmaxf(t, 0.0f);
        s0 = fmaf(t, aw2[hh * 3 + 0], s0);
        s1 = fmaf(t, aw2[hh * 3 + 1], s1);
        s2 = fmaf(t, aw2[hh * 3 + 2], s2);
    }

    const float w0 = v0 + e0, w1 = v1 + e1, w2 = v2 + e2;

    float m0 = s0, m1 = s1, m2 = s2;
#pragma unroll
    for (int off = 1; off < 16; off <<= 1) {
        m0 = fmaxf(m0, __shfl_xor(m0, off));
        m1 = fmaxf(m1, __shfl_xor(m1, off));
        m2 = fmaxf(m2, __shfl_xor(m2, off));
    }
    const float ex0 = __expf(s0 - m0), ex1 = __expf(s1 - m1), ex2 = __expf(s2 - m2);
    float n0 = ex0 * w0, n1 = ex1 * w1, n2 = ex2 * w2;
    float den0 = ex0, den1 = ex1, den2 = ex2;
#pragma unroll
    for (int off = 1; off < 16; off <<= 1) {
        den0 += __shfl_xor(den0, off); n0 += __shfl_xor(n0, off);
        den1 += __shfl_xor(den1, off); n1 += __shfl_xor(n1, off);
        den2 += __shfl_xor(den2, off); n2 += __shfl_xor(n2, off);
    }

    if (j == 0) {
        const float h0 = 1.f / (1.f + __expf(-(n0 / den0)));
        const float h1 = 1.f / (1.f + __expf(-(n1 / den1)));
        const float h2 = 1.f / (1.f + __expf(-(n2 / den2)));
        if (!last) {
            hout[qg * 3 + 0] = h0;
            hout[qg * 3 + 1] = h1;
            hout[qg * 3 + 2] = h2;
        } else {
            const float o0 = fmaf(h0, lw[0], fmaf(h1, lw[2], fmaf(h2, lw[4], lb[0])));
            const float o1 = fmaf(h0, lw[1], fmaf(h1, lw[3], fmaf(h2, lw[5], lb[1])));
            const float mm = fmaxf(o0, o1);
            const float ea = __expf(o0 - mm), eb = __expf(o1 - mm);
            const float inv = 1.f / (ea + eb);
            out[qg * 2 + 0] = ea * inv;
            out[qg * 2 + 1] = eb * inv;
        }
    }
}

// ---------------- launch ----------------
extern "C" void kernel_launch(void* const* d_in, const int* in_sizes, int n_in,
                              void* d_out, int out_size, void* d_ws, size_t ws_size,
                              hipStream_t stream) {
    const float* feats = (const float*)d_in[0];
    const float* pos   = (const float*)d_in[1];
    const float* wqkv = (const float*)d_in[3];
    const float* pw1  = (const float*)d_in[4];
    const float* pb1  = (const float*)d_in[5];
    const float* pw2  = (const float*)d_in[6];
    const float* pb2  = (const float*)d_in[7];
    const float* aw1  = (const float*)d_in[8];
    const float* ab1  = (const float*)d_in[9];
    const float* aw2  = (const float*)d_in[10];
    const float* ab2  = (const float*)d_in[11];
    const float* lw   = (const float*)d_in[12];
    const float* lb   = (const float*)d_in[13];
    float* out = (float*)d_out;

    size_t o = 0;
    auto take = [&](size_t bytes) { size_t r = o; o += (bytes + 15) & ~(size_t)15; return r; };
    const size_t o_cnt   = take((size_t)(2 * MCELL + 4) * 4);  // cnt | cnt2 | ovf_cnt
    const size_t o_scan  = take((size_t)MCELL * 4);
    const size_t o_cs    = take((size_t)(MCELL + 1) * 4);
    const size_t o_bsum  = take((size_t)256 * 4);
    const size_t o_cid   = take((size_t)NQ * 4);
    const size_t o_spp   = take((size_t)NQ * 16);
    const size_t o_sidx  = take((size_t)NQ * 4);
    const size_t o_knn   = take((size_t)NQ * KNB * 4);
    const size_t o_ovfl  = take((size_t)NQ * 4);
    const size_t o_hA    = take((size_t)NQ * 3 * 4);
    const size_t o_hB    = take((size_t)NQ * 3 * 4);
    const size_t o_pbuf  = take((size_t)WCAP * NCHK * KNB * 8);  // 8 MB
    if (ws_size < o) return;

    char* ws = (char*)d_ws;
    int*    cnt     = (int*)(ws + o_cnt);
    int*    cnt2    = cnt + MCELL;
    int*    ovf_cnt = cnt + 2 * MCELL;
    int*    scan  = (int*)(ws + o_scan);
    int*    cs    = (int*)(ws + o_cs);
    int*    bsum  = (int*)(ws + o_bsum);
    int*    cid   = (int*)(ws + o_cid);
    float4* spp   = (float4*)(ws + o_spp);
    int*    sidx  = (int*)(ws + o_sidx);
    int*    knn   = (int*)(ws + o_knn);
    int*    ovfl  = (int*)(ws + o_ovfl);
    float*  hA    = (float*)(ws + o_hA);
    float*  hB    = (float*)(ws + o_hB);
    u64*    pbuf  = (u64*)(ws + o_pbuf);

    const int nscan = (MCELL + 1023) / 1024;

    kzero<<<(2 * MCELL + 1 + 255) / 256, 256, 0, stream>>>(cnt, 2 * MCELL + 1);
    kcount<<<NQ / 256, 256, 0, stream>>>(pos, cnt, cid);
    kscan1<<<nscan, 1024, 0, stream>>>(cnt, scan, bsum);
    kscan2<<<nscan, 1024, 0, stream>>>(scan, bsum, cs);
    kscatter<<<NQ / 256, 256, 0, stream>>>(pos, cid, cs, cnt2, spp, sidx);
    ksearch_fast<<<NQ / 4, 64, 0, stream>>>(spp, sidx, cs, knn, ovfl, ovf_cnt);
    kslow_scan<<<SCANG, 64, 0, stream>>>(spp, sidx, ovfl, ovf_cnt, pbuf);
    kslow_merge<<<MERGG, 64, 0, stream>>>(spp, sidx, knn, ovfl, ovf_cnt, pbuf);

    pt_layer_f<<<NQ * 16 / 256, 256, 0, stream>>>(feats, pos, knn,
        wqkv + 0, pw1 + 0, pb1 + 0, pw2 + 0, pb2 + 0,
        aw1 + 0, ab1 + 0, aw2 + 0, ab2 + 0,
        hA, lw, lb, out, 0);
    pt_layer_f<<<NQ * 16 / 256, 256, 0, stream>>>(hA, pos, knn,
        wqkv + 27, pw1 + 96, pb1 + 32, pw2 + 96, pb2 + 3,
        aw1 + 36, ab1 + 12, aw2 + 36, ab2 + 3,
        hB, lw, lb, out, 0);
    pt_layer_f<<<NQ * 16 / 256, 256, 0, stream>>>(hB, pos, knn,
        wqkv + 54, pw1 + 192, pb1 + 64, pw2 + 192, pb2 + 6,
        aw1 + 72, ab1 + 24, aw2 + 72, ab2 + 6,
        hB, lw, lb, out, 1);
}

// Round 13
// 125.552 us; speedup vs baseline: 1.4960x; 1.0963x over previous
//
#include <hip/hip_runtime.h>
#include <math.h>

#define N_PTS 8192
#define BATCH 2
#define KNB 16
#define NQ (BATCH * N_PTS)          // 16384

// spatial grid
#define H    0.35f
#define INVH (1.0f / 0.35f)
#define NC   30
#define LBOX (0.5f * H * NC)        // 5.25
#define NCELL (NC * NC * NC)        // 27000
#define MCELL (2 * NCELL)           // 54000 (both batches)
#define NROW1 9                     // box R<=1 rows per query
#define NROWT 43                    // + 34 shell-2 ranges
#define NCHK 8                      // slow-path chunks per query (1024 pts each)
#define CHKP (N_PTS / NCHK)         // 1024
#define SCANG 8192                  // slow-scan grid (one task per wave)
#define MERGG 1024                  // slow-merge grid
#define WCAP 8192                   // pbuf capacity in queries (8 MB)

typedef unsigned long long u64;

__device__ __forceinline__ float med3f(float a, float b, float c) {
#if __has_builtin(__builtin_amdgcn_fmed3f)
    return __builtin_amdgcn_fmed3f(a, b, c);
#else
    return fmaxf(fminf(a, b), fminf(fmaxf(a, b), c));
#endif
}

__device__ __forceinline__ unsigned sortable(float x) {
    unsigned u = __float_as_uint(x);
    return u ^ ((unsigned)((int)u >> 31) | 0x80000000u);
}

// guarded u64 16-slot sorted insert (descending; pk[0]=max kept)
__device__ __forceinline__ void ins_u64(u64 (&pk)[KNB], u64 key) {
    if (key < pk[0]) {
#pragma unroll
        for (int s = 0; s < KNB; ++s) {
            const u64 ds1 = (s < KNB - 1) ? pk[s + 1] : 0ull;
            const bool c0 = key < pk[s];
            const bool c1 = key < ds1;
            pk[s] = c1 ? ds1 : (c0 ? key : pk[s]);
        }
    }
}

// static 16-element bitonic sort network, DESCENDING (a[0]=max).
__device__ __forceinline__ void sort16_desc_u64(u64 (&a)[KNB]) {
#pragma unroll
    for (int k = 2; k <= 16; k <<= 1) {
#pragma unroll
        for (int j = k >> 1; j > 0; j >>= 1) {
#pragma unroll
            for (int i = 0; i < 16; ++i) {
                const int l = i ^ j;
                if (l > i) {
                    const bool dirDesc = ((i & k) == 0);
                    const u64 mx = a[i] > a[l] ? a[i] : a[l];
                    const u64 mn = a[i] > a[l] ? a[l] : a[i];
                    a[i] = dirDesc ? mx : mn;
                    a[l] = dirDesc ? mn : mx;
                }
            }
        }
    }
}

// 64-lane bitonic merge of per-lane sorted-desc u64[16]
__device__ __forceinline__ void merge64_u64(u64 (&pk)[KNB]) {
#pragma unroll
    for (int mm = 1; mm <= 32; mm <<= 1) {
        u64 L[KNB];
#pragma unroll
        for (int i = 0; i < KNB; ++i) {
            const u64 a = pk[i];
            const u64 c = __shfl_xor(pk[KNB - 1 - i], mm);
            L[i] = a < c ? a : c;
        }
#pragma unroll
        for (int dd = 8; dd >= 1; dd >>= 1) {
#pragma unroll
            for (int i = 0; i < KNB; ++i) {
                if ((i & dd) == 0) {
                    const u64 hi = L[i] > L[i | dd] ? L[i] : L[i | dd];
                    const u64 lo = L[i] > L[i | dd] ? L[i | dd] : L[i];
                    L[i] = hi; L[i | dd] = lo;
                }
            }
        }
#pragma unroll
        for (int i = 0; i < KNB; ++i) pk[i] = L[i];
    }
}

// ---------------- zero counters ----------------
__global__ __launch_bounds__(256) void kzero(int* __restrict__ p, int n) {
    const int i = blockIdx.x * 256 + threadIdx.x;
    if (i < n) p[i] = 0;
}

// ---------------- count points per cell ----------------
__global__ __launch_bounds__(256) void kcount(const float* __restrict__ pos,
                                              int* __restrict__ cnt,
                                              int* __restrict__ cellid) {
    const int g = blockIdx.x * 256 + threadIdx.x;
    const int b = g >> 13;
    const float x = pos[g * 3 + 0], y = pos[g * 3 + 1], z = pos[g * 3 + 2];
    int cx = (int)floorf((x + LBOX) * INVH); cx = min(max(cx, 0), NC - 1);
    int cy = (int)floorf((y + LBOX) * INVH); cy = min(max(cy, 0), NC - 1);
    int cz = (int)floorf((z + LBOX) * INVH); cz = min(max(cz, 0), NC - 1);
    const int c = (((b * NC) + cz) * NC + cy) * NC + cx;
    cellid[g] = c;
    atomicAdd(&cnt[c], 1);
}

// ---------------- prefix sum, level 1 ----------------
__global__ __launch_bounds__(1024) void kscan1(const int* __restrict__ cnt,
                                               int* __restrict__ scanned,
                                               int* __restrict__ bsum) {
    __shared__ int sh[1024];
    const int t = threadIdx.x;
    const int idx = blockIdx.x * 1024 + t;
    int v = (idx < MCELL) ? cnt[idx] : 0;
    sh[t] = v;
    __syncthreads();
    for (int off = 1; off < 1024; off <<= 1) {
        const int add = (t >= off) ? sh[t - off] : 0;
        __syncthreads();
        sh[t] += add;
        __syncthreads();
    }
    if (idx < MCELL) scanned[idx] = sh[t];
    if (t == 1023) bsum[blockIdx.x] = sh[1023];
}

// ---------------- prefix sum, level 2 ----------------
__global__ __launch_bounds__(1024) void kscan2(const int* __restrict__ scanned,
                                               const int* __restrict__ bsum,
                                               int* __restrict__ cell_start) {
    __shared__ int soff;
    const int t = threadIdx.x;
    const int blk = blockIdx.x;
    const int idx = blk * 1024 + t;
    if (t == 0) {
        int s = 0;
        for (int k = 0; k < blk; ++k) s += bsum[k];
        soff = s;
    }
    __syncthreads();
    if (idx < MCELL) cell_start[idx + 1] = scanned[idx] + soff;
    if (idx == 0) cell_start[0] = 0;
}

// ---------------- scatter points into cell-sorted order ----------------
__global__ __launch_bounds__(256) void kscatter(const float* __restrict__ pos,
                                                const int* __restrict__ cellid,
                                                const int* __restrict__ cell_start,
                                                int* __restrict__ cnt2,
                                                float4* __restrict__ spp,
                                                int* __restrict__ sidx) {
    const int g = blockIdx.x * 256 + threadIdx.x;
    const int c = cellid[g];
    const int off = atomicAdd(&cnt2[c], 1);
    const int p = cell_start[c] + off;
    const float x = pos[g * 3 + 0], y = pos[g * 3 + 1], z = pos[g * 3 + 2];
    spp[p] = make_float4(-2.f * x, -2.f * y, -2.f * z, fmaf(x, x, fmaf(y, y, z * z)));
    sidx[p] = g & (N_PTS - 1);
}

// ---------------- fast kNN: 16 lanes/query, LDS row ranges, box batches ----------------
// Phase A: all cs[] row-range loads for the block's 4 queries issued in
// PARALLEL across 64 lanes into LDS (kills the serial cs->cs->spp chain that
// dominated the old ring walk). Scan box R<=1 (9 rows), bound-test; if
// needed scan shell R=2 (34 ranges), bound-test; else overflow.
// Pass-1 insert is BRANCHLESS (med3 chain is a no-op for x >= d[0], all 16
// med3 independent) so spp gathers pipeline. Pass-2 as before.
__global__ __launch_bounds__(64) void ksearch_fast(const float4* __restrict__ spp,
                                                   const int* __restrict__ sidx,
                                                   const int* __restrict__ cs,
                                                   int* __restrict__ knn,
                                                   int* __restrict__ ovf_list,
                                                   int* __restrict__ ovf_cnt) {
    __shared__ int rst[4][NROWT], ren[4][NROWT];
    const int tid = threadIdx.x;
    const int li  = tid & 15;
    const int gq  = tid >> 4;
    const int sq  = blockIdx.x * 4 + gq;
    const int b   = sq >> 13;

    // ---- Phase A: cooperative range loads ----
    for (int t = tid; t < 4 * NROWT; t += 64) {
        const int q = t / NROWT, r = t % NROWT;
        const int sq2 = blockIdx.x * 4 + q;
        const int b2  = sq2 >> 13;
        const float4 m2 = spp[sq2];
        const float px = -0.5f * m2.x, py = -0.5f * m2.y, pz = -0.5f * m2.z;
        int c2x = (int)floorf((px + LBOX) * INVH); c2x = min(max(c2x, 0), NC - 1);
        int c2y = (int)floorf((py + LBOX) * INVH); c2y = min(max(c2y, 0), NC - 1);
        int c2z = (int)floorf((pz + LBOX) * INVH); c2z = min(max(c2z, 0), NC - 1);

        int st = 0, en = 0;
        int z, y, xlo, xhi;
        bool ok = true;
        if (r < NROW1) {                       // box R<=1: 3x3 rows, x in [cx-1,cx+1]
            z = c2z + r / 3 - 1;
            y = c2y + (r % 3) - 1;
            xlo = max(c2x - 1, 0); xhi = min(c2x + 1, NC - 1);
        } else {
            const int rr = r - NROW1;          // shell R=2 (98 cells as 34 ranges)
            if (rr < 10) {                     // z = cz±2 planes: 10 full rows
                z = c2z + (rr < 5 ? -2 : 2);
                y = c2y + (rr % 5) - 2;
                xlo = max(c2x - 2, 0); xhi = min(c2x + 2, NC - 1);
            } else if (rr < 16) {              // inner z, y = cy±2: 6 full rows
                const int k = rr - 10;
                z = c2z + (k % 3) - 1;
                y = c2y + (k < 3 ? -2 : 2);
                xlo = max(c2x - 2, 0); xhi = min(c2x + 2, NC - 1);
            } else {                           // inner z,y; x = cx±2: 18 single cells
                const int k = rr - 16;
                const int m = k % 9;
                z = c2z + m / 3 - 1;
                y = c2y + (m % 3) - 1;
                const int xx = c2x + (k < 9 ? -2 : 2);
                xlo = xhi = xx;
                ok = (xx >= 0) && (xx < NC);   // no clamp: clamped cell would duplicate box
            }
        }
        if (ok && z >= 0 && z < NC && y >= 0 && y < NC) {
            const int rowb = (((b2 * NC) + z) * NC + y) * NC;
            st = cs[rowb + xlo];
            en = cs[rowb + xhi + 1];
        }
        rst[q][r] = st; ren[q][r] = en;
    }
    __syncthreads();

    const float4 me = spp[sq];
    const float qx = -0.5f * me.x, qy = -0.5f * me.y, qz = -0.5f * me.z;
    const float qsq = me.w;
    int cx = (int)floorf((qx + LBOX) * INVH); cx = min(max(cx, 0), NC - 1);
    int cy = (int)floorf((qy + LBOX) * INVH); cy = min(max(cy, 0), NC - 1);
    int cz = (int)floorf((qz + LBOX) * INVH); cz = min(max(cz, 0), NC - 1);

    // ---- pass 1: branchless float med3 top-16 over LDS-ranged rows ----
    float d[KNB];
#pragma unroll
    for (int k = 0; k < KNB; ++k) d[k] = 3.4e38f;

    auto scan1_rows = [&](int r0, int r1) {
        for (int r = r0; r < r1; ++r) {
            const int st = rst[gq][r], en = ren[gq][r];
            for (int p = st + li; p < en; p += 16) {
                const float4 v = spp[p];
                const float x = fmaf(qx, v.x, fmaf(qy, v.y, fmaf(qz, v.z, v.w)));
#pragma unroll
                for (int s = 0; s < KNB - 1; ++s) d[s] = med3f(d[s], d[s + 1], x);
                d[KNB - 1] = fminf(d[KNB - 1], x);
            }
        }
    };

    auto boundtest = [&](int R) -> bool {
        const float bxl = fmaf((float)(cx - R), H, -LBOX);
        const float bxh = fmaf((float)(cx + R + 1), H, -LBOX);
        const float byl = fmaf((float)(cy - R), H, -LBOX);
        const float byh = fmaf((float)(cy + R + 1), H, -LBOX);
        const float bzl = fmaf((float)(cz - R), H, -LBOX);
        const float bzh = fmaf((float)(cz + R + 1), H, -LBOX);
        const float m = fminf(fminf(fminf(qx - bxl, bxh - qx),
                                    fminf(qy - byl, byh - qy)),
                              fminf(qz - bzl, bzh - qz));
        if (!(m > 0.f)) return false;
        const float Bf = fmaf(m, m, -1e-4f) - qsq;
        int c = 0;
#pragma unroll
        for (int k = 0; k < KNB; ++k) c += (d[k] <= Bf) ? 1 : 0;
#pragma unroll
        for (int off = 1; off < 16; off <<= 1) c += __shfl_xor(c, off);
        return c >= KNB;
    };

    scan1_rows(0, NROW1);
    const bool done1 = boundtest(1);
    bool ovf = false;
    if (!done1) {
        scan1_rows(NROW1, NROWT);
        if (!boundtest(2)) ovf = true;
    }
    if (ovf) {
        if (li == 0) { const int s2 = atomicAdd(ovf_cnt, 1); ovf_list[s2] = sq; }
        return;
    }
    const int nrows = done1 ? NROW1 : NROWT;

    // ---- merge per-lane float tops -> exact global 16th-smallest key ----
#pragma unroll
    for (int mm = 1; mm <= 8; mm <<= 1) {
        float L[KNB];
#pragma unroll
        for (int i = 0; i < KNB; ++i)
            L[i] = fminf(d[i], __shfl_xor(d[KNB - 1 - i], mm));
#pragma unroll
        for (int dd = 8; dd >= 1; dd >>= 1) {
#pragma unroll
            for (int i = 0; i < KNB; ++i) {
                if ((i & dd) == 0) {
                    const float hi = fmaxf(L[i], L[i | dd]);
                    const float lo = fminf(L[i], L[i | dd]);
                    L[i] = hi; L[i | dd] = lo;
                }
            }
        }
#pragma unroll
        for (int i = 0; i < KNB; ++i) d[i] = L[i];
    }
    const float thr = d[0];

    // ---- pass 2: exact (key,idx) top-16 among x <= thr ----
    u64 pk[KNB];
#pragma unroll
    for (int k = 0; k < KNB; ++k) pk[k] = 0xFFFFFFFFFFFFFFFFull;

    for (int r = 0; r < nrows; ++r) {
        const int st = rst[gq][r], en = ren[gq][r];
        for (int p = st + li; p < en; p += 16) {
            const float4 v = spp[p];
            const float x = fmaf(qx, v.x, fmaf(qy, v.y, fmaf(qz, v.z, v.w)));
            if (x <= thr) {
                ins_u64(pk, ((u64)sortable(x) << 32) | (unsigned)sidx[p]);
            }
        }
    }

    // ---- u64 16-lane bitonic merge -> exact global top-16 (key,idx) ----
#pragma unroll
    for (int mm = 1; mm <= 8; mm <<= 1) {
        u64 L[KNB];
#pragma unroll
        for (int i = 0; i < KNB; ++i) {
            const u64 a = pk[i];
            const u64 c = __shfl_xor(pk[KNB - 1 - i], mm);
            L[i] = a < c ? a : c;
        }
#pragma unroll
        for (int dd = 8; dd >= 1; dd >>= 1) {
#pragma unroll
            for (int i = 0; i < KNB; ++i) {
                if ((i & dd) == 0) {
                    const u64 hi = L[i] > L[i | dd] ? L[i] : L[i | dd];
                    const u64 lo = L[i] > L[i | dd] ? L[i | dd] : L[i];
                    L[i] = hi; L[i | dd] = lo;
                }
            }
        }
#pragma unroll
        for (int i = 0; i < KNB; ++i) pk[i] = L[i];
    }

    const int qorig = sidx[sq];
    const int obase = ((b << 13) + qorig) * KNB;
    u64 sel = pk[0];
#pragma unroll
    for (int s = 1; s < KNB; ++s) sel = (li == s) ? pk[s] : sel;
    knn[obase + li] = (int)(unsigned)(sel & 0xFFFFFFFFull);
}

// ---------------- slow kNN scan: one wave per (overflow query, 1024-pt chunk) ----------------
__global__ __launch_bounds__(64, 4) void kslow_scan(const float4* __restrict__ spp,
                                                    const int* __restrict__ sidx,
                                                    const int* __restrict__ ovf_list,
                                                    const int* __restrict__ ovf_cnt,
                                                    u64* __restrict__ pbuf) {
    const int lane = threadIdx.x;
    const int ntask = min(*ovf_cnt, WCAP) * NCHK;

    for (int task = blockIdx.x; task < ntask; task += SCANG) {
        const int w = task >> 3;
        const int c = task & (NCHK - 1);
        const int sq = ovf_list[w];
        const int b  = sq >> 13;
        const float4 me = spp[sq];
        const float qx = -0.5f * me.x, qy = -0.5f * me.y, qz = -0.5f * me.z;
        const int cbase = (b << 13) + c * CHKP;

        u64 pk[KNB];
#pragma unroll
        for (int t0 = 0; t0 < 2; ++t0) {
            const int tb = cbase + lane + t0 * 512;
            float4 v[8];
            int id[8];
#pragma unroll
            for (int u = 0; u < 8; ++u) v[u] = spp[tb + u * 64];
#pragma unroll
            for (int u = 0; u < 8; ++u) id[u] = sidx[tb + u * 64];
#pragma unroll
            for (int u = 0; u < 8; ++u) {
                const float x = fmaf(qx, v[u].x, fmaf(qy, v[u].y, fmaf(qz, v[u].z, v[u].w)));
                pk[t0 * 8 + u] = ((u64)sortable(x) << 32) | (unsigned)id[u];
            }
        }

        sort16_desc_u64(pk);
        merge64_u64(pk);

        u64 sel = pk[0];
#pragma unroll
        for (int s = 1; s < KNB; ++s) sel = (lane == s) ? pk[s] : sel;
        if (lane < KNB) pbuf[(size_t)task * KNB + lane] = sel;
    }
}

// ---------------- slow kNN merge: one wave per overflow query ----------------
__global__ __launch_bounds__(64) void kslow_merge(const float4* __restrict__ spp,
                                                  const int* __restrict__ sidx,
                                                  int* __restrict__ knn,
                                                  const int* __restrict__ ovf_list,
                                                  const int* __restrict__ ovf_cnt,
                                                  const u64* __restrict__ pbuf) {
    const int lane = threadIdx.x;
    const int nov = *ovf_cnt;

    for (int w = blockIdx.x; w < nov; w += MERGG) {
        const int sq = ovf_list[w];
        const int b  = sq >> 13;

        u64 pk[KNB];
#pragma unroll
        for (int k = 0; k < KNB; ++k) pk[k] = 0xFFFFFFFFFFFFFFFFull;

        if (w < WCAP) {
            const u64 a0 = pbuf[(size_t)w * (NCHK * KNB) + lane];
            const u64 a1 = pbuf[(size_t)w * (NCHK * KNB) + 64 + lane];
            ins_u64(pk, a0);
            ins_u64(pk, a1);
        } else {
            const float4 me = spp[sq];
            const float qx = -0.5f * me.x, qy = -0.5f * me.y, qz = -0.5f * me.z;
            const int base = b << 13;
            unsigned smax = 0xFFFFFFFFu;
            for (int t = lane; t < N_PTS; t += 64) {
                const float4 v = spp[base + t];
                const float x = fmaf(qx, v.x, fmaf(qy, v.y, fmaf(qz, v.z, v.w)));
                const unsigned sx = sortable(x);
                if (sx <= smax) {
                    ins_u64(pk, ((u64)sx << 32) | (unsigned)sidx[base + t]);
                    smax = (unsigned)(pk[0] >> 32);
                }
            }
        }

        merge64_u64(pk);

        const int qorig = sidx[sq];
        const int obase = ((b << 13) + qorig) * KNB;
        u64 sel = pk[0];
#pragma unroll
        for (int s = 1; s < KNB; ++s) sel = (lane == s) ? pk[s] : sel;
        if (lane < KNB) knn[obase + lane] = (int)(unsigned)(sel & 0xFFFFFFFFull);
    }
}

// ---------------- fused PT layer: per-edge MLPs + 16-lane shuffle softmax ----------------
__global__ __launch_bounds__(256) void pt_layer_f(const float* __restrict__ hin,
                                                  const float* __restrict__ pos,
                                                  const int* __restrict__ knn,
                                                  const float* __restrict__ wqkv,
                                                  const float* __restrict__ pw1,
                                                  const float* __restrict__ pb1,
                                                  const float* __restrict__ pw2,
                                                  const float* __restrict__ pb2,
                                                  const float* __restrict__ aw1,
                                                  const float* __restrict__ ab1,
                                                  const float* __restrict__ aw2,
                                                  const float* __restrict__ ab2,
                                                  float* __restrict__ hout,
                                                  const float* __restrict__ lw,
                                                  const float* __restrict__ lb,
                                                  float* __restrict__ out,
                                                  int last) {
    const int gt = blockIdx.x * 256 + threadIdx.x;
    const int qg = gt >> 4;
    const int j  = gt & 15;
    const int b  = qg >> 13;
    const int jj = knn[qg * KNB + j] & (N_PTS - 1);
    const int g  = (b << 13) + jj;

    const float hi0 = hin[qg * 3 + 0], hi1 = hin[qg * 3 + 1], hi2 = hin[qg * 3 + 2];
    const float hj0 = hin[g * 3 + 0],  hj1 = hin[g * 3 + 1],  hj2 = hin[g * 3 + 2];
    const float rx = pos[qg * 3 + 0] - pos[g * 3 + 0];
    const float ry = pos[qg * 3 + 1] - pos[g * 3 + 1];
    const float rz = pos[qg * 3 + 2] - pos[g * 3 + 2];

    const float q0 = fmaf(hi0, wqkv[0], fmaf(hi1, wqkv[9],  hi2 * wqkv[18]));
    const float q1 = fmaf(hi0, wqkv[1], fmaf(hi1, wqkv[10], hi2 * wqkv[19]));
    const float q2 = fmaf(hi0, wqkv[2], fmaf(hi1, wqkv[11], hi2 * wqkv[20]));
    const float k0 = fmaf(hj0, wqkv[3], fmaf(hj1, wqkv[12], hj2 * wqkv[21]));
    const float k1 = fmaf(hj0, wqkv[4], fmaf(hj1, wqkv[13], hj2 * wqkv[22]));
    const float k2 = fmaf(hj0, wqkv[5], fmaf(hj1, wqkv[14], hj2 * wqkv[23]));
    const float v0 = fmaf(hj0, wqkv[6], fmaf(hj1, wqkv[15], hj2 * wqkv[24]));
    const float v1 = fmaf(hj0, wqkv[7], fmaf(hj1, wqkv[16], hj2 * wqkv[25]));
    const float v2 = fmaf(hj0, wqkv[8], fmaf(hj1, wqkv[17], hj2 * wqkv[26]));

    float e0 = pb2[0], e1 = pb2[1], e2 = pb2[2];
#pragma unroll
    for (int hh = 0; hh < 32; ++hh) {
        float t = fmaf(rx, pw1[hh], fmaf(ry, pw1[32 + hh], fmaf(rz, pw1[64 + hh], pb1[hh])));
        t = fmaxf(t, 0.0f);
        e0 = fmaf(t, pw2[hh * 3 + 0], e0);
        e1 = fmaf(t, pw2[hh * 3 + 1], e1);
        e2 = fmaf(t, pw2[hh * 3 + 2], e2);
    }

    const float x0 = q0 - k0 + e0;
    const float x1 = q1 - k1 + e1;
    const float x2 = q2 - k2 + e2;

    float s0 = ab2[0], s1 = ab2[1], s2 = ab2[2];
#pragma unroll
    for (int hh = 0; hh < 12; ++hh) {
        float t = fmaf(x0, aw1[hh], fmaf(x1, aw1[12 + hh], fmaf(x2, aw1[24 + hh], ab1[hh])));
        t = fmaxf(t, 0.0f);
        s0 = fmaf(t, aw2[hh * 3 + 0], s0);
        s1 = fmaf(t, aw2[hh * 3 + 1], s1);
        s2 = fmaf(t, aw2[hh * 3 + 2], s2);
    }

    const float w0 = v0 + e0, w1 = v1 + e1, w2 = v2 + e2;

    float m0 = s0, m1 = s1, m2 = s2;
#pragma unroll
    for (int off = 1; off < 16; off <<= 1) {
        m0 = fmaxf(m0, __shfl_xor(m0, off));
        m1 = fmaxf(m1, __shfl_xor(m1, off));
        m2 = fmaxf(m2, __shfl_xor(m2, off));
    }
    const float ex0 = __expf(s0 - m0), ex1 = __expf(s1 - m1), ex2 = __expf(s2 - m2);
    float n0 = ex0 * w0, n1 = ex1 * w1, n2 = ex2 * w2;
    float den0 = ex0, den1 = ex1, den2 = ex2;
#pragma unroll
    for (int off = 1; off < 16; off <<= 1) {
        den0 += __shfl_xor(den0, off); n0 += __shfl_xor(n0, off);
        den1 += __shfl_xor(den1, off); n1 += __shfl_xor(n1, off);
        den2 += __shfl_xor(den2, off); n2 += __shfl_xor(n2, off);
    }

    if (j == 0) {
        const float h0 = 1.f / (1.f + __expf(-(n0 / den0)));
        const float h1 = 1.f / (1.f + __expf(-(n1 / den1)));
        const float h2 = 1.f / (1.f + __expf(-(n2 / den2)));
        if (!last) {
            hout[qg * 3 + 0] = h0;
            hout[qg * 3 + 1] = h1;
            hout[qg * 3 + 2] = h2;
        } else {
            const float o0 = fmaf(h0, lw[0], fmaf(h1, lw[2], fmaf(h2, lw[4], lb[0])));
            const float o1 = fmaf(h0, lw[1], fmaf(h1, lw[3], fmaf(h2, lw[5], lb[1])));
            const float mm = fmaxf(o0, o1);
            const float ea = __expf(o0 - mm), eb = __expf(o1 - mm);
            const float inv = 1.f / (ea + eb);
            out[qg * 2 + 0] = ea * inv;
            out[qg * 2 + 1] = eb * inv;
        }
    }
}

// ---------------- launch ----------------
extern "C" void kernel_launch(void* const* d_in, const int* in_sizes, int n_in,
                              void* d_out, int out_size, void* d_ws, size_t ws_size,
                              hipStream_t stream) {
    const float* feats = (const float*)d_in[0];
    const float* pos   = (const float*)d_in[1];
    const float* wqkv = (const float*)d_in[3];
    const float* pw1  = (const float*)d_in[4];
    const float* pb1  = (const float*)d_in[5];
    const float* pw2  = (const float*)d_in[6];
    const float* pb2  = (const float*)d_in[7];
    const float* aw1  = (const float*)d_in[8];
    const float* ab1  = (const float*)d_in[9];
    const float* aw2  = (const float*)d_in[10];
    const float* ab2  = (const float*)d_in[11];
    const float* lw   = (const float*)d_in[12];
    const float* lb   = (const float*)d_in[13];
    float* out = (float*)d_out;

    size_t o = 0;
    auto take = [&](size_t bytes) { size_t r = o; o += (bytes + 15) & ~(size_t)15; return r; };
    const size_t o_cnt   = take((size_t)(2 * MCELL + 4) * 4);  // cnt | cnt2 | ovf_cnt
    const size_t o_scan  = take((size_t)MCELL * 4);
    const size_t o_cs    = take((size_t)(MCELL + 1) * 4);
    const size_t o_bsum  = take((size_t)256 * 4);
    const size_t o_cid   = take((size_t)NQ * 4);
    const size_t o_spp   = take((size_t)NQ * 16);
    const size_t o_sidx  = take((size_t)NQ * 4);
    const size_t o_knn   = take((size_t)NQ * KNB * 4);
    const size_t o_ovfl  = take((size_t)NQ * 4);
    const size_t o_hA    = take((size_t)NQ * 3 * 4);
    const size_t o_hB    = take((size_t)NQ * 3 * 4);
    const size_t o_pbuf  = take((size_t)WCAP * NCHK * KNB * 8);  // 8 MB
    if (ws_size < o) return;

    char* ws = (char*)d_ws;
    int*    cnt     = (int*)(ws + o_cnt);
    int*    cnt2    = cnt + MCELL;
    int*    ovf_cnt = cnt + 2 * MCELL;
    int*    scan  = (int*)(ws + o_scan);
    int*    cs    = (int*)(ws + o_cs);
    int*    bsum  = (int*)(ws + o_bsum);
    int*    cid   = (int*)(ws + o_cid);
    float4* spp   = (float4*)(ws + o_spp);
    int*    sidx  = (int*)(ws + o_sidx);
    int*    knn   = (int*)(ws + o_knn);
    int*    ovfl  = (int*)(ws + o_ovfl);
    float*  hA    = (float*)(ws + o_hA);
    float*  hB    = (float*)(ws + o_hB);
    u64*    pbuf  = (u64*)(ws + o_pbuf);

    const int nscan = (MCELL + 1023) / 1024;

    kzero<<<(2 * MCELL + 1 + 255) / 256, 256, 0, stream>>>(cnt, 2 * MCELL + 1);
    kcount<<<NQ / 256, 256, 0, stream>>>(pos, cnt, cid);
    kscan1<<<nscan, 1024, 0, stream>>>(cnt, scan, bsum);
    kscan2<<<nscan, 1024, 0, stream>>>(scan, bsum, cs);
    kscatter<<<NQ / 256, 256, 0, stream>>>(pos, cid, cs, cnt2, spp, sidx);
    ksearch_fast<<<NQ / 4, 64, 0, stream>>>(spp, sidx, cs, knn, ovfl, ovf_cnt);
    kslow_scan<<<SCANG, 64, 0, stream>>>(spp, sidx, ovfl, ovf_cnt, pbuf);
    kslow_merge<<<MERGG, 64, 0, stream>>>(spp, sidx, knn, ovfl, ovf_cnt, pbuf);

    pt_layer_f<<<NQ * 16 / 256, 256, 0, stream>>>(feats, pos, knn,
        wqkv + 0, pw1 + 0, pb1 + 0, pw2 + 0, pb2 + 0,
        aw1 + 0, ab1 + 0, aw2 + 0, ab2 + 0,
        hA, lw, lb, out, 0);
    pt_layer_f<<<NQ * 16 / 256, 256, 0, stream>>>(hA, pos, knn,
        wqkv + 27, pw1 + 96, pb1 + 32, pw2 + 96, pb2 + 3,
        aw1 + 36, ab1 + 12, aw2 + 36, ab2 + 3,
        hB, lw, lb, out, 0);
    pt_layer_f<<<NQ * 16 / 256, 256, 0, stream>>>(hB, pos, knn,
        wqkv + 54, pw1 + 192, pb1 + 64, pw2 + 192, pb2 + 6,
        aw1 + 72, ab1 + 24, aw2 + 72, ab2 + 6,
        hB, lw, lb, out, 1);
}